// Round 8
// baseline (197.675 us; speedup 1.0000x reference)
//
#include <hip/hip_runtime.h>
#include <hip/hip_bf16.h>
#include <stdint.h>

// Problem constants (B=4, L=4096, D=1024, K=3)
#define B_SZ   4
#define L_SEQ  4096
#define D_DIM  1024
#define M_TOT  (B_SZ * L_SEQ)   // 16384

typedef __bf16 bf16;
typedef __attribute__((ext_vector_type(8))) __bf16 bf16x8;
typedef __attribute__((ext_vector_type(4))) float   f32x4;

#define GLOAD_LDS16(g, l)                                                     \
  __builtin_amdgcn_global_load_lds(                                           \
      (const __attribute__((address_space(1))) void*)(g),                     \
      (__attribute__((address_space(3))) void*)(l), 16, 0, 0)

// ---------------------------------------------------------------------------
// Kernel 1 (VERBATIM, proven): causal depthwise conv (K=3) + bf16 cast.
// Blocks >= M_TOT/16 do w_pw fp32->bf16 (bf16 B keeps the GEMM's B operand
// at 2MB so it stays XCD-L2-resident).
// ---------------------------------------------------------------------------
__global__ __launch_bounds__(256) void dw_bf16_kernel(
    const float* __restrict__ x, const float* __restrict__ w_dw,
    const float* __restrict__ b_dw, bf16* __restrict__ y,
    const float* __restrict__ w_pw, bf16* __restrict__ wpwb) {
  const int t = threadIdx.x;
  if (blockIdx.x >= B_SZ * (L_SEQ / 16)) {
    int i = ((blockIdx.x - B_SZ * (L_SEQ / 16)) * 256 + t) * 8;
    float4 a = *(const float4*)(w_pw + i);
    float4 b = *(const float4*)(w_pw + i + 4);
    union { bf16 h[8]; int4 v; } r;
    r.h[0] = (bf16)a.x; r.h[1] = (bf16)a.y; r.h[2] = (bf16)a.z; r.h[3] = (bf16)a.w;
    r.h[4] = (bf16)b.x; r.h[5] = (bf16)b.y; r.h[6] = (bf16)b.z; r.h[7] = (bf16)b.w;
    *(int4*)(wpwb + i) = r.v;
    return;
  }
  const int b  = blockIdx.x >> 8;     // / (L_SEQ/16 = 256)
  const int l0 = (blockIdx.x & 255) * 16;
  const int d0 = t * 4;
  const float* xb = x + (size_t)b * L_SEQ * D_DIM + d0;
  bf16*        yb = y + (size_t)b * L_SEQ * D_DIM + d0;

  float4 xr[18];
  const float4 zero = make_float4(0.f, 0.f, 0.f, 0.f);
  xr[0] = (l0 >= 2) ? *(const float4*)(xb + (size_t)(l0 - 2) * D_DIM) : zero;
  xr[1] = (l0 >= 1) ? *(const float4*)(xb + (size_t)(l0 - 1) * D_DIM) : zero;
#pragma unroll
  for (int j = 0; j < 16; ++j)
    xr[j + 2] = *(const float4*)(xb + (size_t)(l0 + j) * D_DIM);

  const float* wp = w_dw + d0 * 3;
  float4 wa = *(const float4*)(wp);      // d0:k0,k1,k2  d1:k0
  float4 wb = *(const float4*)(wp + 4);  // d1:k1,k2     d2:k0,k1
  float4 wc = *(const float4*)(wp + 8);  // d2:k2        d3:k0,k1,k2
  float4 bv = *(const float4*)(b_dw + d0);

#pragma unroll
  for (int j = 0; j < 16; ++j) {
    float4 x2 = xr[j], x1 = xr[j + 1], x0 = xr[j + 2];
    float a0 = fmaf(x2.x, wa.x, fmaf(x1.x, wa.y, fmaf(x0.x, wa.z, bv.x)));
    float a1 = fmaf(x2.y, wa.w, fmaf(x1.y, wb.x, fmaf(x0.y, wb.y, bv.y)));
    float a2 = fmaf(x2.z, wb.z, fmaf(x1.z, wb.w, fmaf(x0.z, wc.x, bv.z)));
    float a3 = fmaf(x2.w, wc.y, fmaf(x1.w, wc.z, fmaf(x0.w, wc.w, bv.w)));
    union { bf16 h[4]; int2 v; } o;
    o.h[0] = (bf16)a0; o.h[1] = (bf16)a1; o.h[2] = (bf16)a2; o.h[3] = (bf16)a3;
    *(int2*)(yb + (size_t)(l0 + j) * D_DIM) = o.v;
  }
}

// ---------------------------------------------------------------------------
// Kernel 2: 256x256 GEMM, 16 waves, A via LDS ring-2, **B DIRECT TO VGPR**.
//   out[m][n] = sum_k y[m][k] * wpwb[n][k] + b_pw[n]
// M=16384, N=1024, K=1024 -> 32 K-slices of 32.
//
// r4-r7 post-mortem: every LDS-staged-B variant lands 42-44us; main-loop
// swizzle proven conflict-free (bank-conflict counter == epilogue-only
// 262144 in all rounds). Slice period ~3150cy vs ~1800cy LDS-port usage:
// everything is coupled to the block-wide VM+barrier rendezvous. This round
// DECOUPLES B: wpwb (2MB bf16) is XCD-L2-resident (read by all 64 m-panels),
// and the 4 waves sharing a wn4 read IDENTICAL B addresses (L1 broadcast).
// B-frags load straight to VGPRs, double-buffered 1 slice ahead, zero
// barrier interaction. LDS traffic/slice halves (160->80KB); DMA queue
// halves (A only); acc-coupled rendezvous deps halve.
//
// A path (proven, unchanged): ring-2 16KB slots, 1 gload_lds/thread/slice,
// swizzle read c'=q^((row>>1)&3) @64B pitch, write side pre-swizzles the
// global source, LDS dest linear.
//
// Wait calculus (FIFO pinned by sched_barrier between A and B issues):
//   body(s) entry: outstanding = {A(s), B(s)x4}; VM(4) retires exactly A(s).
//   SB (rendezvous; 4 loads remain in flight - never drained to 0).
//   ds_read af(slot s&1); stage_A(s+1) [1 DMA]; SCB; loadB(s+1)x4; SCB;
//   VM(5) retires exactly B(s)x4 (leaves {A(s+1), B(s+1)x4}).
//   16 MFMA (af x B(s) regs).
// Ring-2 overwrite safety: slot (s+1)&1's previous readers (slice s-1) are
// lgkm-retired before each wave's MFMA(s-1), hence before it reaches SB(s);
// stage_A(s+1) issues only after SB(s) rendezvous. Tail: VM(0) before
// MFMA(31). Slices unrolled x2 (even->bA, odd->bB) for static reg indexing.
//
// GRID (m=x fastest): XCD = bx%8 -> all 4 n-blocks of an m-panel share an
// XCD (A fetched ~once from HBM; B L2-resident).
// ---------------------------------------------------------------------------
#define EP_ROWP 68
#define SB  __builtin_amdgcn_s_barrier()
#define SCB __builtin_amdgcn_sched_barrier(0)
#define VM(N) asm volatile("s_waitcnt vmcnt(" #N ")" ::: "memory")

__global__ __launch_bounds__(1024, 4) void gemm256_kernel(
    const bf16* __restrict__ A,   // M x K row-major (y, bf16)
    const bf16* __restrict__ Bm,  // N x K row-major (wpwb, bf16)
    const float* __restrict__ bias, float* __restrict__ C) {
  __shared__ __align__(16) char smem[69632];  // ring-2 A: 32KB; epilogue: 68KB

  const int t    = threadIdx.x;
  const int m0   = blockIdx.x * 256;  // grid.x = 64 (m) — fastest
  const int n0   = blockIdx.y * 256;  // grid.y = 4 (n)
  const int lane = t & 63;
  const int wv   = t >> 6;    // 0..15
  const int wm4  = wv >> 2;   // 0..3: m-quarter (64 rows)
  const int wn4  = wv & 3;    // 0..3: n-quarter (64 cols)
  const int lrow = lane & 15;
  const int q    = lane >> 4;

  // A frag read base within a slot: row*64 + c'*16, c' = q ^ ((row>>1)&3)
  const unsigned cx    = (((unsigned)q ^ (((unsigned)lrow >> 1) & 3)) << 4);
  const unsigned baseA = (unsigned)((wm4 * 64 + lrow) * 64) + cx;

  // A stage source (pre-swizzled global), LDS dest linear:
  // granule g = t: row = t>>2 (0..255), gc = (t&3) ^ ((row>>1)&3)
  const int grow = t >> 2;
  const int gc   = (t & 3) ^ ((grow >> 1) & 3);
  const bf16* aSrc = A + (size_t)(m0 + grow) * D_DIM + gc * 8;
  const unsigned wbase = (unsigned)(wv * 1024);   // wave-uniform LDS part

  // B direct-load base: lane (q,lrow), frag j: row n0+wn4*64+j*16+lrow, k q*8
  const bf16* bPtr = Bm + (size_t)(n0 + wn4 * 64 + lrow) * D_DIM + q * 8;

  auto stage_a = [&](int s) {   // 1 gload_lds per thread = 16KB slice
    GLOAD_LDS16(aSrc + (size_t)s * 32, smem + (unsigned)((s & 1) * 16384) + wbase);
  };

  f32x4 acc[4][4] = {};
  bf16x8 bA[4], bB[4];

#define LOADB(dst, s) do {                                                    \
    _Pragma("unroll")                                                         \
    for (int j = 0; j < 4; ++j)                                               \
      dst[j] = *(const bf16x8*)(bPtr + (size_t)j * 16 * D_DIM + (size_t)(s) * 32); \
  } while (0)

  // one slice; bcur = regs holding B(s); bnxt = regs to fill with B(s+1)
  auto body = [&](int s, bf16x8* bcur, bf16x8* bnxt, int mode) {
    // mode 0: steady (stage+load, VM5) | 1: last-stage (load only, VM4) |
    // mode 2: tail (no issues, VM0)
    SB;                                   // slot s&1 proven (VM(4) before)
    const char* Ab = smem + (size_t)((s & 1) * 16384);
    bf16x8 af[4];
#pragma unroll
    for (int i = 0; i < 4; ++i) af[i] = *(const bf16x8*)(Ab + baseA + i * 1024);
    if (mode == 0) { stage_a(s + 1); SCB; LOADB((*(bf16x8(*)[4])bnxt), s + 1); SCB; VM(5); }
    else if (mode == 1) { LOADB((*(bf16x8(*)[4])bnxt), s + 1); SCB; VM(4); }
    else { VM(0); }
    __builtin_amdgcn_s_setprio(1);
#pragma unroll
    for (int i = 0; i < 4; ++i)
#pragma unroll
      for (int j = 0; j < 4; ++j)
        acc[i][j] = __builtin_amdgcn_mfma_f32_16x16x32_bf16(af[i], bcur[j], acc[i][j], 0, 0, 0);
    __builtin_amdgcn_s_setprio(0);
    SCB;
  };

  // prologue: A(0) DMA + B(0) regs in flight (5 outstanding)
  stage_a(0); SCB;
  LOADB(bA, 0); SCB;

  // slices 0..29 (even->bA, odd->bB), steady mode
#pragma unroll 1
  for (int s = 0; s < 30; s += 2) {
    VM(4); body(s, bA, bB, 0);       // uses B(s)=bA, loads B(s+1)->bB
    VM(4); body(s + 1, bB, bA, 0);   // uses bB, loads B(s+2)->bA
  }
  // slice 30: stage nothing more for A? A(31) staged by slice-30 steady?
  // slice 30 in steady staged A(31) and B(31) already via loop? No: loop
  // covered s=0..29, so A(30),B(30) staged by s=29; slice 30 must stage
  // A(31)+B(31) -> but A(31) via stage_a(31): mode 0 at s=30 would also
  // VM(5) correctly. Then slice 31 = tail.
  VM(4); body(30, bA, bB, 0);        // stages A(31), loads B(31)->bB, VM(5)
  VM(4); body(31, bB, bA, 2);        // VM(4) retires A(31); VM(0) -> B(31)

  // --- epilogue: per-wave LDS transpose, then coalesced float4 stores ---
  SB;   // all waves' slice-31 reads retired before reaching this barrier
  float* ep = (float*)smem + (size_t)wv * (16 * EP_ROWP);  // wave-private 4352B

  float bvj[4];
#pragma unroll
  for (int j = 0; j < 4; ++j) bvj[j] = bias[n0 + wn4 * 64 + j * 16 + lrow];

#pragma unroll
  for (int i = 0; i < 4; ++i) {
#pragma unroll
    for (int j = 0; j < 4; ++j)
#pragma unroll
      for (int r = 0; r < 4; ++r)
        ep[(q * 4 + r) * EP_ROWP + j * 16 + lrow] = acc[i][j][r] + bvj[j];
    // wave-private region: in-wave DS program order suffices, no barrier
#pragma unroll
    for (int it2 = 0; it2 < 4; ++it2) {
      int flat = it2 * 64 + lane;
      int row  = flat >> 4;
      int c16  = flat & 15;
      float4 v = *(const float4*)(ep + row * EP_ROWP + c16 * 4);
      int gm = m0 + wm4 * 64 + i * 16 + row;
      int gn = n0 + wn4 * 64 + c16 * 4;
      *(float4*)(C + (size_t)gm * D_DIM + gn) = v;
    }
  }
#undef LOADB
}

// ---------------------------------------------------------------------------
// Fallback (only if workspace is too small): correct but slow fp32 path.
// ---------------------------------------------------------------------------
__global__ __launch_bounds__(256) void fallback_kernel(
    const float* __restrict__ x, const float* __restrict__ w_dw,
    const float* __restrict__ b_dw, const float* __restrict__ w_pw,
    const float* __restrict__ b_pw, float* __restrict__ out) {
  __shared__ float ys[D_DIM];
  const int m = blockIdx.x;
  const int l = m & (L_SEQ - 1);
  const int t = threadIdx.x;
  const float* xr = x + (size_t)m * D_DIM;
#pragma unroll
  for (int c = 0; c < 4; ++c) {
    int d = t + c * 256;
    float a = fmaf(xr[d], w_dw[d * 3 + 2], b_dw[d]);
    if (l >= 1) a = fmaf(xr[d - D_DIM], w_dw[d * 3 + 1], a);
    if (l >= 2) a = fmaf(xr[d - 2 * D_DIM], w_dw[d * 3 + 0], a);
    ys[d] = a;
  }
  __syncthreads();
#pragma unroll
  for (int c = 0; c < 4; ++c) {
    int e = t + c * 256;
    const float* wr = w_pw + (size_t)e * D_DIM;
    float a = b_pw[e];
    for (int d = 0; d < D_DIM; ++d) a = fmaf(ys[d], wr[d], a);
    out[(size_t)m * D_DIM + e] = a;
  }
}

extern "C" void kernel_launch(void* const* d_in, const int* in_sizes, int n_in,
                              void* d_out, int out_size, void* d_ws, size_t ws_size,
                              hipStream_t stream) {
  (void)in_sizes; (void)n_in; (void)out_size;
  const float* x    = (const float*)d_in[0];
  const float* w_dw = (const float*)d_in[1];
  const float* b_dw = (const float*)d_in[2];
  const float* w_pw = (const float*)d_in[3];
  const float* b_pw = (const float*)d_in[4];
  float* out = (float*)d_out;

  const size_t y_elems = (size_t)M_TOT * D_DIM;          // 16M bf16 = 32 MB
  const size_t w_elems = (size_t)D_DIM * D_DIM;          // 1M bf16  =  2 MB
  const size_t need = (y_elems + w_elems) * sizeof(bf16);

  if (ws_size >= need) {
    bf16* y    = (bf16*)d_ws;
    bf16* wpwb = (bf16*)d_ws + y_elems;
    const int dw_blocks  = B_SZ * (L_SEQ / 16);          // 1024
    const int cvt_blocks = (D_DIM * D_DIM / 8) / 256;    // 512
    dw_bf16_kernel<<<dw_blocks + cvt_blocks, 256, 0, stream>>>(x, w_dw, b_dw, y, w_pw, wpwb);
    dim3 grid(M_TOT / 256, D_DIM / 256);                 // (64, 4): m fastest
    gemm256_kernel<<<grid, 1024, 0, stream>>>(y, wpwb, b_pw, out);
  } else {
    fallback_kernel<<<M_TOT, 256, 0, stream>>>(x, w_dw, b_dw, w_pw, b_pw, out);
  }
}

// Round 9
// 161.052 us; speedup vs baseline: 1.2274x; 1.2274x over previous
//
#include <hip/hip_runtime.h>
#include <hip/hip_bf16.h>
#include <stdint.h>

// Problem constants (B=4, L=4096, D=1024, K=3)
#define B_SZ   4
#define L_SEQ  4096
#define D_DIM  1024
#define M_TOT  (B_SZ * L_SEQ)   // 16384

typedef __bf16 bf16;
typedef __attribute__((ext_vector_type(8))) __bf16 bf16x8;
typedef __attribute__((ext_vector_type(4))) float   f32x4;

#define GLOAD_LDS16(g, l)                                                     \
  __builtin_amdgcn_global_load_lds(                                           \
      (const __attribute__((address_space(1))) void*)(g),                     \
      (__attribute__((address_space(3))) void*)(l), 16, 0, 0)

// ---------------------------------------------------------------------------
// Kernel 1: causal depthwise conv (K=3) + bf16 cast (proven path, unchanged).
// cvt branch CHANGED: writes wpwb in MFMA-FRAGMENT ORDER so the GEMM can load
// B-frags coalesced straight to VGPRs (fixes r8's 64-line gather):
//   granule G = (((nb*4+wn4)*32+s)*4+j)*64+lane  (16B each) holds
//   w_pw[nb*256+wn4*64+j*16+(lane&15)][s*32+(lane>>4)*8 .. +8] as bf16x8.
// ---------------------------------------------------------------------------
__global__ __launch_bounds__(256) void dw_bf16_kernel(
    const float* __restrict__ x, const float* __restrict__ w_dw,
    const float* __restrict__ b_dw, bf16* __restrict__ y,
    const float* __restrict__ w_pw, bf16* __restrict__ wpwb) {
  const int t = threadIdx.x;
  if (blockIdx.x >= B_SZ * (L_SEQ / 16)) {
    // frag-order cvt: 512 blocks x 256 thr = 131072 granules of 16B
    int g    = (blockIdx.x - B_SZ * (L_SEQ / 16)) * 256 + t;
    int lane = g & 63;
    int j    = (g >> 6) & 3;
    int s    = (g >> 8) & 31;
    int wn4f = (g >> 13) & 3;
    int nb   = g >> 15;
    int row  = nb * 256 + wn4f * 64 + j * 16 + (lane & 15);
    int col  = s * 32 + (lane >> 4) * 8;
    const float* src = w_pw + (size_t)row * D_DIM + col;
    float4 a = *(const float4*)(src);
    float4 b = *(const float4*)(src + 4);
    union { bf16 h[8]; int4 v; } r;
    r.h[0] = (bf16)a.x; r.h[1] = (bf16)a.y; r.h[2] = (bf16)a.z; r.h[3] = (bf16)a.w;
    r.h[4] = (bf16)b.x; r.h[5] = (bf16)b.y; r.h[6] = (bf16)b.z; r.h[7] = (bf16)b.w;
    *(int4*)(wpwb + (size_t)g * 8) = r.v;
    return;
  }
  const int b  = blockIdx.x >> 8;     // / (L_SEQ/16 = 256)
  const int l0 = (blockIdx.x & 255) * 16;
  const int d0 = t * 4;
  const float* xb = x + (size_t)b * L_SEQ * D_DIM + d0;
  bf16*        yb = y + (size_t)b * L_SEQ * D_DIM + d0;

  float4 xr[18];
  const float4 zero = make_float4(0.f, 0.f, 0.f, 0.f);
  xr[0] = (l0 >= 2) ? *(const float4*)(xb + (size_t)(l0 - 2) * D_DIM) : zero;
  xr[1] = (l0 >= 1) ? *(const float4*)(xb + (size_t)(l0 - 1) * D_DIM) : zero;
#pragma unroll
  for (int j = 0; j < 16; ++j)
    xr[j + 2] = *(const float4*)(xb + (size_t)(l0 + j) * D_DIM);

  const float* wp = w_dw + d0 * 3;
  float4 wa = *(const float4*)(wp);      // d0:k0,k1,k2  d1:k0
  float4 wb = *(const float4*)(wp + 4);  // d1:k1,k2     d2:k0,k1
  float4 wc = *(const float4*)(wp + 8);  // d2:k2        d3:k0,k1,k2
  float4 bv = *(const float4*)(b_dw + d0);

#pragma unroll
  for (int j = 0; j < 16; ++j) {
    float4 x2 = xr[j], x1 = xr[j + 1], x0 = xr[j + 2];
    float a0 = fmaf(x2.x, wa.x, fmaf(x1.x, wa.y, fmaf(x0.x, wa.z, bv.x)));
    float a1 = fmaf(x2.y, wa.w, fmaf(x1.y, wb.x, fmaf(x0.y, wb.y, bv.y)));
    float a2 = fmaf(x2.z, wb.z, fmaf(x1.z, wb.w, fmaf(x0.z, wc.x, bv.z)));
    float a3 = fmaf(x2.w, wc.y, fmaf(x1.w, wc.z, fmaf(x0.w, wc.w, bv.w)));
    union { bf16 h[4]; int2 v; } o;
    o.h[0] = (bf16)a0; o.h[1] = (bf16)a1; o.h[2] = (bf16)a2; o.h[3] = (bf16)a3;
    *(int2*)(yb + (size_t)(l0 + j) * D_DIM) = o.v;
  }
}

// ---------------------------------------------------------------------------
// Kernel 2: 256x256 GEMM, 16 waves; A via LDS ring-2 (r6's proven path),
// B via COALESCED frag-order direct-to-VGPR loads (r8 structure, gather fixed).
//   out[m][n] = sum_k y[m][k] * wpwb_frag[n][k] + b_pw[n]
//
// r6 post-mortem: main loop ~84% LDS-port-occupied (160KB/slice). r8 proved
// the reg-B VM calculus correct but its 2KB-stride gather serialized L1
// (~64 lines/instr). Fix: wpwb pre-laid in fragment order -> each B-frag
// load is 64 lanes x 16B CONTIGUOUS (1KB run), L2-resident (2MB), and the 4
// waves sharing wn4 read identical addresses (16KB/slice fits L1). LDS
// traffic/slice halves: 160 -> 80KB.
//
// Wait calculus (r8-proven, FIFO pinned by SCB):
//   entry VM(4) retires A(s) exactly (B(s)x4 remain). SB. ds_read af(slot
//   s&1); stage_A(s+1) [1 DMA]; SCB; loadB(s+1)x4 coalesced; SCB; VM(5)
//   retires B(s)x4 (leaves A(s+1)+B(s+1)x4). 16 MFMA on af x B(s)-regs.
// Ring-2 A overwrite safety: slot (s+1)&1's previous readers (slice s-1)
// lgkm-retired before each wave's MFMA(s-1), hence before SB(s); stage
// issues after SB(s). Tail: entry VM(4) retires A(31); VM(0) -> B(31).
//
// Swizzle (A, proven): read c' = q^((row>>1)&3) @64B pitch; global source
// pre-swizzled; LDS dest linear. GRID (m=x fastest): XCD = bx%8.
// ---------------------------------------------------------------------------
#define EP_ROWP 68
#define SB  __builtin_amdgcn_s_barrier()
#define SCB __builtin_amdgcn_sched_barrier(0)
#define VM(N) asm volatile("s_waitcnt vmcnt(" #N ")" ::: "memory")

__global__ __launch_bounds__(1024, 4) void gemm256_kernel(
    const bf16* __restrict__ A,    // M x K row-major (y, bf16)
    const bf16* __restrict__ Bf,   // frag-ordered wpwb
    const float* __restrict__ bias, float* __restrict__ C) {
  __shared__ __align__(16) char smem[69632];  // ring-2 A 32KB; epilogue 68KB

  const int t    = threadIdx.x;
  const int m0   = blockIdx.x * 256;  // grid.x = 64 (m) — fastest
  const int nb   = blockIdx.y;        // grid.y = 4 (n)
  const int n0   = nb * 256;
  const int lane = t & 63;
  const int wv   = t >> 6;    // 0..15
  const int wm4  = wv >> 2;   // 0..3: m-quarter (64 rows)
  const int wn4  = wv & 3;    // 0..3: n-quarter (64 cols)
  const int lrow = lane & 15;
  const int q    = lane >> 4;

  // A frag read base within a slot: row*64 + c'*16, c' = q ^ ((row>>1)&3)
  const unsigned cx    = (((unsigned)q ^ (((unsigned)lrow >> 1) & 3)) << 4);
  const unsigned baseA = (unsigned)((wm4 * 64 + lrow) * 64) + cx;

  // A stage source (pre-swizzled global), LDS dest linear:
  // granule g = t: row = t>>2 (0..255), gc = (t&3) ^ ((row>>1)&3)
  const int grow = t >> 2;
  const int gc   = (t & 3) ^ ((grow >> 1) & 3);
  const bf16* aSrc = A + (size_t)(m0 + grow) * D_DIM + gc * 8;
  const unsigned wbase = (unsigned)(wv * 1024);   // wave-uniform LDS part

  // B frag base (bf16-element offsets): granule G*16B layout ->
  // elem = (nb*4+wn4)*65536 + lane*8 + s*2048 + j*512
  const bf16* bBase = Bf + (size_t)(nb * 4 + wn4) * 65536 + lane * 8;

  auto stage_a = [&](int s) {   // 1 gload_lds per thread = 16KB slice
    GLOAD_LDS16(aSrc + (size_t)s * 32, smem + (unsigned)((s & 1) * 16384) + wbase);
  };

  f32x4 acc[4][4] = {};
  bf16x8 bA[4], bB[4];

#define LOADB(dst, s) do {                                                    \
    _Pragma("unroll")                                                         \
    for (int j = 0; j < 4; ++j)                                               \
      dst[j] = *(const bf16x8*)(bBase + (size_t)(s) * 2048 + j * 512);        \
  } while (0)

  // one slice; bcur = regs holding B(s); bnxt = regs to fill with B(s+1)
  auto body = [&](int s, bf16x8* bcur, bf16x8* bnxt, int mode) {
    // mode 0: steady (stage+load, VM5) | 2: tail (no issues, VM0)
    SB;                                   // slot s&1 proven (VM(4) at entry)
    const char* Ab = smem + (size_t)((s & 1) * 16384);
    bf16x8 af[4];
#pragma unroll
    for (int i = 0; i < 4; ++i) af[i] = *(const bf16x8*)(Ab + baseA + i * 1024);
    if (mode == 0) { stage_a(s + 1); SCB; LOADB((*(bf16x8(*)[4])bnxt), s + 1); SCB; VM(5); }
    else { VM(0); }
    __builtin_amdgcn_s_setprio(1);
#pragma unroll
    for (int i = 0; i < 4; ++i)
#pragma unroll
      for (int j = 0; j < 4; ++j)
        acc[i][j] = __builtin_amdgcn_mfma_f32_16x16x32_bf16(af[i], bcur[j], acc[i][j], 0, 0, 0);
    __builtin_amdgcn_s_setprio(0);
    SCB;
  };

  // prologue: A(0) DMA + B(0) regs in flight (5 outstanding)
  stage_a(0); SCB;
  LOADB(bA, 0); SCB;

#pragma unroll 1
  for (int s = 0; s < 30; s += 2) {
    VM(4); body(s, bA, bB, 0);       // retires A(s); uses bA, loads B(s+1)->bB
    VM(4); body(s + 1, bB, bA, 0);   // retires A(s+1); uses bB, loads ->bA
  }
  VM(4); body(30, bA, bB, 0);        // stages A(31), loads B(31)->bB
  VM(4); body(31, bB, bA, 2);        // entry retires A(31); VM(0) -> B(31)

  // --- epilogue: per-wave LDS transpose, then coalesced float4 stores ---
  SB;   // all waves' slice-31 LDS reads retired before this barrier
  float* ep = (float*)smem + (size_t)wv * (16 * EP_ROWP);  // wave-private 4352B

  float bvj[4];
#pragma unroll
  for (int j = 0; j < 4; ++j) bvj[j] = bias[n0 + wn4 * 64 + j * 16 + lrow];

#pragma unroll
  for (int i = 0; i < 4; ++i) {
#pragma unroll
    for (int j = 0; j < 4; ++j)
#pragma unroll
      for (int r = 0; r < 4; ++r)
        ep[(q * 4 + r) * EP_ROWP + j * 16 + lrow] = acc[i][j][r] + bvj[j];
    // wave-private region: in-wave DS program order suffices, no barrier
#pragma unroll
    for (int it2 = 0; it2 < 4; ++it2) {
      int flat = it2 * 64 + lane;
      int row  = flat >> 4;
      int c16  = flat & 15;
      float4 v = *(const float4*)(ep + row * EP_ROWP + c16 * 4);
      int gm = m0 + wm4 * 64 + i * 16 + row;
      int gn = n0 + wn4 * 64 + c16 * 4;
      *(float4*)(C + (size_t)gm * D_DIM + gn) = v;
    }
  }
#undef LOADB
}

// ---------------------------------------------------------------------------
// Fallback (only if workspace is too small): correct but slow fp32 path.
// ---------------------------------------------------------------------------
__global__ __launch_bounds__(256) void fallback_kernel(
    const float* __restrict__ x, const float* __restrict__ w_dw,
    const float* __restrict__ b_dw, const float* __restrict__ w_pw,
    const float* __restrict__ b_pw, float* __restrict__ out) {
  __shared__ float ys[D_DIM];
  const int m = blockIdx.x;
  const int l = m & (L_SEQ - 1);
  const int t = threadIdx.x;
  const float* xr = x + (size_t)m * D_DIM;
#pragma unroll
  for (int c = 0; c < 4; ++c) {
    int d = t + c * 256;
    float a = fmaf(xr[d], w_dw[d * 3 + 2], b_dw[d]);
    if (l >= 1) a = fmaf(xr[d - D_DIM], w_dw[d * 3 + 1], a);
    if (l >= 2) a = fmaf(xr[d - 2 * D_DIM], w_dw[d * 3 + 0], a);
    ys[d] = a;
  }
  __syncthreads();
#pragma unroll
  for (int c = 0; c < 4; ++c) {
    int e = t + c * 256;
    const float* wr = w_pw + (size_t)e * D_DIM;
    float a = b_pw[e];
    for (int d = 0; d < D_DIM; ++d) a = fmaf(ys[d], wr[d], a);
    out[(size_t)m * D_DIM + e] = a;
  }
}

extern "C" void kernel_launch(void* const* d_in, const int* in_sizes, int n_in,
                              void* d_out, int out_size, void* d_ws, size_t ws_size,
                              hipStream_t stream) {
  (void)in_sizes; (void)n_in; (void)out_size;
  const float* x    = (const float*)d_in[0];
  const float* w_dw = (const float*)d_in[1];
  const float* b_dw = (const float*)d_in[2];
  const float* w_pw = (const float*)d_in[3];
  const float* b_pw = (const float*)d_in[4];
  float* out = (float*)d_out;

  const size_t y_elems = (size_t)M_TOT * D_DIM;          // 16M bf16 = 32 MB
  const size_t w_elems = (size_t)D_DIM * D_DIM;          // 1M bf16  =  2 MB
  const size_t need = (y_elems + w_elems) * sizeof(bf16);

  if (ws_size >= need) {
    bf16* y    = (bf16*)d_ws;
    bf16* wpwb = (bf16*)d_ws + y_elems;
    const int dw_blocks  = B_SZ * (L_SEQ / 16);          // 1024
    const int cvt_blocks = (D_DIM * D_DIM / 8) / 256;    // 512
    dw_bf16_kernel<<<dw_blocks + cvt_blocks, 256, 0, stream>>>(x, w_dw, b_dw, y, w_pw, wpwb);
    dim3 grid(M_TOT / 256, D_DIM / 256);                 // (64, 4): m fastest
    gemm256_kernel<<<grid, 1024, 0, stream>>>(y, wpwb, b_pw, out);
  } else {
    fallback_kernel<<<M_TOT, 256, 0, stream>>>(x, w_dw, b_dw, w_pw, b_pw, out);
  }
}

// Round 10
// 156.087 us; speedup vs baseline: 1.2664x; 1.0318x over previous
//
#include <hip/hip_runtime.h>
#include <hip/hip_bf16.h>
#include <stdint.h>

// Problem constants (B=4, L=4096, D=1024, K=3)
#define B_SZ   4
#define L_SEQ  4096
#define D_DIM  1024
#define M_TOT  (B_SZ * L_SEQ)   // 16384

typedef __bf16 bf16;
typedef __attribute__((ext_vector_type(8))) __bf16 bf16x8;
typedef __attribute__((ext_vector_type(4))) float   f32x4;

#define GLOAD_LDS16(g, l)                                                     \
  __builtin_amdgcn_global_load_lds(                                           \
      (const __attribute__((address_space(1))) void*)(g),                     \
      (__attribute__((address_space(3))) void*)(l), 16, 0, 0)

// ---------------------------------------------------------------------------
// Kernel 1: causal depthwise conv (K=3) + bf16 cast.
// r9 post-mortem: GEMM is plateaued at r6's 42us; dw (~28us vs ~16us traffic
// floor) is the remaining budget. Change: 8 channels/thread (128 thr span
// D=1024; block = two 8-row halves), rolling 3-row window, int4 16B stores
// (was int2 8B) — store instruction count halves, loads stay float4.
// Causal guard: only l0==0/half==0 zeroes rows -2/-1; half 1's halo rows
// (l0+6, l0+7) are always in-batch. cvt branch: r6 VERBATIM (row-major bf16
// wpwb, 2MB, XCD-L2-resident for the GEMM).
// ---------------------------------------------------------------------------
__global__ __launch_bounds__(256) void dw_bf16_kernel(
    const float* __restrict__ x, const float* __restrict__ w_dw,
    const float* __restrict__ b_dw, bf16* __restrict__ y,
    const float* __restrict__ w_pw, bf16* __restrict__ wpwb) {
  const int t = threadIdx.x;
  if (blockIdx.x >= B_SZ * (L_SEQ / 16)) {
    int i = ((blockIdx.x - B_SZ * (L_SEQ / 16)) * 256 + t) * 8;
    float4 a = *(const float4*)(w_pw + i);
    float4 b = *(const float4*)(w_pw + i + 4);
    union { bf16 h[8]; int4 v; } r;
    r.h[0] = (bf16)a.x; r.h[1] = (bf16)a.y; r.h[2] = (bf16)a.z; r.h[3] = (bf16)a.w;
    r.h[4] = (bf16)b.x; r.h[5] = (bf16)b.y; r.h[6] = (bf16)b.z; r.h[7] = (bf16)b.w;
    *(int4*)(wpwb + i) = r.v;
    return;
  }
  const int b    = blockIdx.x >> 8;     // / (L_SEQ/16 = 256)
  const int l0   = (blockIdx.x & 255) * 16;
  const int half = t >> 7;              // 0..1: 8-row half
  const int tid  = t & 127;
  const int d0   = tid * 8;
  const int r0   = l0 + half * 8;
  const float* xb = x + (size_t)b * L_SEQ * D_DIM + d0;
  bf16*        yb = y + (size_t)b * L_SEQ * D_DIM + d0;

  struct F8 { float f[8]; };
  F8 x0, x1, x2;
  const bool edge = (l0 == 0) && (half == 0);   // rows -2/-1 are pre-batch
  if (edge) {
#pragma unroll
    for (int c = 0; c < 8; ++c) { x0.f[c] = 0.f; x1.f[c] = 0.f; }
  } else {
    *(float4*)&x0.f[0] = *(const float4*)(xb + (size_t)(r0 - 2) * D_DIM);
    *(float4*)&x0.f[4] = *(const float4*)(xb + (size_t)(r0 - 2) * D_DIM + 4);
    *(float4*)&x1.f[0] = *(const float4*)(xb + (size_t)(r0 - 1) * D_DIM);
    *(float4*)&x1.f[4] = *(const float4*)(xb + (size_t)(r0 - 1) * D_DIM + 4);
  }

  // weights: 8 ch x 3 = 24 contiguous floats at w_dw + d0*3 (96B-aligned)
  float wf[24];
#pragma unroll
  for (int v = 0; v < 6; ++v)
    *(float4*)&wf[v * 4] = *(const float4*)(w_dw + d0 * 3 + v * 4);
  float bf[8];
  *(float4*)&bf[0] = *(const float4*)(b_dw + d0);
  *(float4*)&bf[4] = *(const float4*)(b_dw + d0 + 4);

#pragma unroll
  for (int j = 0; j < 8; ++j) {
    *(float4*)&x2.f[0] = *(const float4*)(xb + (size_t)(r0 + j) * D_DIM);
    *(float4*)&x2.f[4] = *(const float4*)(xb + (size_t)(r0 + j) * D_DIM + 4);
    union { bf16 h[8]; int4 v; } o;
#pragma unroll
    for (int c = 0; c < 8; ++c)
      o.h[c] = (bf16)fmaf(x0.f[c], wf[c * 3],
                 fmaf(x1.f[c], wf[c * 3 + 1],
                   fmaf(x2.f[c], wf[c * 3 + 2], bf[c])));
    *(int4*)(yb + (size_t)(r0 + j) * D_DIM) = o.v;
    x0 = x1; x1 = x2;
  }
}

// ---------------------------------------------------------------------------
// Kernel 2 (r6 VERBATIM — best measured: 42us, MfmaUtil 31%):
// 256x256 GEMM, K-slice ring-4, 16 waves (4 waves/SIMD TLP).
//   out[m][n] = sum_k y[m][k] * wpwb[n][k] + b_pw[n]
// M=16384, N=1024, K=1024 -> 32 K-slices of 32.
// Ring: slice s in slot s&3; A-slots 0..64K, B-slots 64K..128K (16KB each).
// Staging: per slice each thread does 1 A + 1 B granule (1024 thr x 16B).
// VM calculus: prologue stages slices 0,1,2 (6/wave); steady VM(4) retires
// slice s's 2 with s+1/s+2 in flight; tail VM(2)/VM(0). Swizzle (proven):
// read c' = q ^ ((row>>1)&3) @64B pitch; global source pre-swizzled; LDS
// dest linear. GRID (m=x fastest): XCD = bx%8 (A fetched ~once; FETCH 24.6MB).
// ---------------------------------------------------------------------------
#define EP_ROWP 68
#define SB  __builtin_amdgcn_s_barrier()
#define SCB __builtin_amdgcn_sched_barrier(0)
#define VM(N) asm volatile("s_waitcnt vmcnt(" #N ")" ::: "memory")

__global__ __launch_bounds__(1024, 4) void gemm256_kernel(
    const bf16* __restrict__ A,   // M x K row-major (y, bf16)
    const bf16* __restrict__ Bm,  // N x K row-major (wpwb, bf16)
    const float* __restrict__ bias, float* __restrict__ C) {
  __shared__ __align__(16) char smem[131072];
  // A-slots: 0,16K,32K,48K ; B-slots: 64K,80K,96K,112K

  const int t    = threadIdx.x;
  const int m0   = blockIdx.x * 256;  // grid.x = 64 (m) — fastest
  const int n0   = blockIdx.y * 256;  // grid.y = 4 (n)
  const int lane = t & 63;
  const int wv   = t >> 6;    // 0..15
  const int wm4  = wv >> 2;   // 0..3: m-quarter (64 rows)
  const int wn4  = wv & 3;    // 0..3: n-quarter (64 cols)
  const int lrow = lane & 15;
  const int q    = lane >> 4;

  const unsigned cx    = (((unsigned)q ^ (((unsigned)lrow >> 1) & 3)) << 4);
  const unsigned baseA = (unsigned)((wm4 * 64 + lrow) * 64) + cx;
  const unsigned baseB = (unsigned)((wn4 * 64 + lrow) * 64) + cx;

  const int grow = t >> 2;
  const int gc   = (t & 3) ^ ((grow >> 1) & 3);
  const bf16* aSrc = A  + (size_t)(m0 + grow) * D_DIM + gc * 8;
  const bf16* bSrc = Bm + (size_t)(n0 + grow) * D_DIM + gc * 8;
  const unsigned wbase = (unsigned)(wv * 1024);   // wave-uniform LDS part

  auto stage = [&](int s) {   // 1 A-granule + 1 B-granule per thread
    const size_t k0 = (size_t)s * 32;
    unsigned as_ = (unsigned)((s & 3) * 16384) + wbase;
    GLOAD_LDS16(aSrc + k0, smem + as_);
    GLOAD_LDS16(bSrc + k0, smem + as_ + 65536);
  };

  f32x4 acc[4][4] = {};

  auto body = [&](int s, bool do_stage) {
    SB;                                  // slot s&3 proven (VM before call)
    const char* Ab = smem + (size_t)((s & 3) * 16384);
    const char* Bb = Ab + 65536;
    bf16x8 af[4], bf4[4];
#pragma unroll
    for (int j = 0; j < 4; ++j) bf4[j] = *(const bf16x8*)(Bb + baseB + j * 1024);
#pragma unroll
    for (int i = 0; i < 4; ++i) af[i]  = *(const bf16x8*)(Ab + baseA + i * 1024);
    if (do_stage) stage(s + 3);
    SCB;
    __builtin_amdgcn_s_setprio(1);
#pragma unroll
    for (int i = 0; i < 4; ++i)
#pragma unroll
      for (int j = 0; j < 4; ++j)
        acc[i][j] = __builtin_amdgcn_mfma_f32_16x16x32_bf16(af[i], bf4[j], acc[i][j], 0, 0, 0);
    __builtin_amdgcn_s_setprio(0);
    SCB;
  };

  // prologue: slices 0,1,2 in flight (6 loads/wave)
  stage(0); stage(1); stage(2);

  for (int s = 0; s < 30; ++s) { VM(4); body(s, s <= 28); }
  VM(2); body(30, false);
  VM(0); body(31, false);

  // --- epilogue: per-wave LDS transpose, then coalesced float4 stores ---
  __syncthreads();   // ep region overlaps A-slot 3 read by slice 31
  float* ep = (float*)smem + (size_t)wv * (16 * EP_ROWP);  // wave-private 4352B

  float bvj[4];
#pragma unroll
  for (int j = 0; j < 4; ++j) bvj[j] = bias[n0 + wn4 * 64 + j * 16 + lrow];

#pragma unroll
  for (int i = 0; i < 4; ++i) {
#pragma unroll
    for (int j = 0; j < 4; ++j)
#pragma unroll
      for (int r = 0; r < 4; ++r)
        ep[(q * 4 + r) * EP_ROWP + j * 16 + lrow] = acc[i][j][r] + bvj[j];
    // wave-private region: in-wave DS program order suffices, no barrier
#pragma unroll
    for (int it2 = 0; it2 < 4; ++it2) {
      int flat = it2 * 64 + lane;
      int row  = flat >> 4;
      int c16  = flat & 15;
      float4 v = *(const float4*)(ep + row * EP_ROWP + c16 * 4);
      int gm = m0 + wm4 * 64 + i * 16 + row;
      int gn = n0 + wn4 * 64 + c16 * 4;
      *(float4*)(C + (size_t)gm * D_DIM + gn) = v;
    }
  }
}

// ---------------------------------------------------------------------------
// Fallback (only if workspace is too small): correct but slow fp32 path.
// ---------------------------------------------------------------------------
__global__ __launch_bounds__(256) void fallback_kernel(
    const float* __restrict__ x, const float* __restrict__ w_dw,
    const float* __restrict__ b_dw, const float* __restrict__ w_pw,
    const float* __restrict__ b_pw, float* __restrict__ out) {
  __shared__ float ys[D_DIM];
  const int m = blockIdx.x;
  const int l = m & (L_SEQ - 1);
  const int t = threadIdx.x;
  const float* xr = x + (size_t)m * D_DIM;
#pragma unroll
  for (int c = 0; c < 4; ++c) {
    int d = t + c * 256;
    float a = fmaf(xr[d], w_dw[d * 3 + 2], b_dw[d]);
    if (l >= 1) a = fmaf(xr[d - D_DIM], w_dw[d * 3 + 1], a);
    if (l >= 2) a = fmaf(xr[d - 2 * D_DIM], w_dw[d * 3 + 0], a);
    ys[d] = a;
  }
  __syncthreads();
#pragma unroll
  for (int c = 0; c < 4; ++c) {
    int e = t + c * 256;
    const float* wr = w_pw + (size_t)e * D_DIM;
    float a = b_pw[e];
    for (int d = 0; d < D_DIM; ++d) a = fmaf(ys[d], wr[d], a);
    out[(size_t)m * D_DIM + e] = a;
  }
}

extern "C" void kernel_launch(void* const* d_in, const int* in_sizes, int n_in,
                              void* d_out, int out_size, void* d_ws, size_t ws_size,
                              hipStream_t stream) {
  (void)in_sizes; (void)n_in; (void)out_size;
  const float* x    = (const float*)d_in[0];
  const float* w_dw = (const float*)d_in[1];
  const float* b_dw = (const float*)d_in[2];
  const float* w_pw = (const float*)d_in[3];
  const float* b_pw = (const float*)d_in[4];
  float* out = (float*)d_out;

  const size_t y_elems = (size_t)M_TOT * D_DIM;          // 16M bf16 = 32 MB
  const size_t w_elems = (size_t)D_DIM * D_DIM;          // 1M bf16  =  2 MB
  const size_t need = (y_elems + w_elems) * sizeof(bf16);

  if (ws_size >= need) {
    bf16* y    = (bf16*)d_ws;
    bf16* wpwb = (bf16*)d_ws + y_elems;
    const int dw_blocks  = B_SZ * (L_SEQ / 16);          // 1024
    const int cvt_blocks = (D_DIM * D_DIM / 8) / 256;    // 512
    dw_bf16_kernel<<<dw_blocks + cvt_blocks, 256, 0, stream>>>(x, w_dw, b_dw, y, w_pw, wpwb);
    dim3 grid(M_TOT / 256, D_DIM / 256);                 // (64, 4): m fastest
    gemm256_kernel<<<grid, 1024, 0, stream>>>(y, wpwb, b_pw, out);
  } else {
    fallback_kernel<<<M_TOT, 256, 0, stream>>>(x, w_dw, b_dw, w_pw, b_pw, out);
  }
}